// Round 1
// baseline (669.032 us; speedup 1.0000x reference)
//
#include <hip/hip_runtime.h>
#include <stdint.h>

#define E_NUM 16
#define T_TOK 512
#define H_DIM 2048
#define I_DIM 1408
#define K_TOP 6
#define CAP   512   // max tokens per expert (dedup guarantees <= T)

#define TM  256     // M-tile: covers all tokens of one expert in one pass (mean Te ~192)
#define TN  32      // N-tile
#define BK  64      // K-chunk (aligns with 128-wide quant blocks: scale uniform per chunk)
#define LDA 72      // padded LDS row stride (+8 elems -> 2-way-only bank aliasing, free)

typedef __attribute__((ext_vector_type(8))) __bf16 bf16x8;
typedef __attribute__((ext_vector_type(4))) float f32x4;
typedef __attribute__((ext_vector_type(4))) unsigned short us4;
typedef __attribute__((ext_vector_type(8))) unsigned short us8;

__device__ __forceinline__ unsigned short f2bf(float f) {
  union { float f; unsigned u; } v; v.f = f;
  unsigned r = v.u + 0x7FFFu + ((v.u >> 16) & 1u);   // RNE
  return (unsigned short)(r >> 16);
}

// ---------- routing: dedup top-k, build per-expert token lists + combine weights ----------
__global__ void k_routing(const float* __restrict__ rw, const int* __restrict__ sel,
                          int* counts, int* list, float* cw) {
  int t = blockIdx.x * blockDim.x + threadIdx.x;
  if (t >= T_TOK) return;
  int e[K_TOP]; float w[K_TOP];
#pragma unroll
  for (int k = 0; k < K_TOP; ++k) { e[k] = sel[t*K_TOP+k]; w[k] = rw[t*K_TOP+k]; }
#pragma unroll
  for (int k = 0; k < K_TOP; ++k) {
    bool dup = false;
#pragma unroll
    for (int j = 0; j < K_TOP; ++j) if (j < k && e[j] == e[k]) dup = true;
    if (!dup) {
      float c = 0.f;
#pragma unroll
      for (int j = 0; j < K_TOP; ++j) if (e[j] == e[k]) c += w[j];
      int slot = atomicAdd(&counts[e[k]], 1);
      list[e[k]*CAP + slot] = t;
      cw[e[k]*CAP + slot] = c;
    }
  }
}

// ---------- x fp32 -> bf16 (2 MB, stays hot in L2/L3 for the gathers) ----------
__global__ void k_xcast(const float* __restrict__ x, unsigned short* __restrict__ xb) {
  int i = blockIdx.x * blockDim.x + threadIdx.x;   // 8 elems per thread
  const float4* src = (const float4*)x;
  float4 v0 = src[2*i], v1 = src[2*i+1];
  us8 o;
  o[0]=f2bf(v0.x); o[1]=f2bf(v0.y); o[2]=f2bf(v0.z); o[3]=f2bf(v0.w);
  o[4]=f2bf(v1.x); o[5]=f2bf(v1.y); o[6]=f2bf(v1.z); o[7]=f2bf(v1.w);
  *(us8*)(xb + (size_t)i*8) = o;
}

// ---------- fused gate+up GEMM + SwiGLU (+combine weight) -> Hbuf bf16 ----------
__global__ __launch_bounds__(256, 2)
void k_gateup(const unsigned short* __restrict__ xb,
              const float* __restrict__ Wg, const float* __restrict__ Sg,
              const float* __restrict__ Wu, const float* __restrict__ Su,
              const int* __restrict__ counts, const int* __restrict__ list,
              const float* __restrict__ cw, unsigned short* __restrict__ Hbuf) {
  __shared__ unsigned short sA[TM * LDA];        // 36 KB
  __shared__ unsigned short sB[2 * TN * LDA];    // 9 KB (gate | up)
  const int e   = blockIdx.y;
  const int n0  = blockIdx.x * TN;
  const int cnt = counts[e];
  if (cnt == 0) return;
  const int tid  = threadIdx.x;
  const int wv   = tid >> 6;
  const int lane = tid & 63;
  const int quad = lane >> 4;
  const int ln   = lane & 15;

  const int*   listE = list + e * CAP;
  const float* cwE   = cw + e * CAP;
  const float* WgE = Wg + (size_t)e * I_DIM * H_DIM + (size_t)n0 * H_DIM;
  const float* WuE = Wu + (size_t)e * I_DIM * H_DIM + (size_t)n0 * H_DIM;
  const float* SgE = Sg + e * (11*16) + (n0 >> 7) * 16;   // (E, I/128, H/128)
  const float* SuE = Su + e * (11*16) + (n0 >> 7) * 16;
  unsigned short* HbE = Hbuf + (size_t)e * CAP * I_DIM;

  for (int m0 = 0; m0 < cnt; m0 += TM) {
    int tok[8];
#pragma unroll
    for (int j = 0; j < 8; ++j) {
      int m = m0 + j*32 + (tid >> 3);
      tok[j] = (m < cnt) ? listE[m] : listE[0];   // clamp padding rows (masked later)
    }
    f32x4 accG[4][2], accU[4][2];
#pragma unroll
    for (int mi = 0; mi < 4; ++mi)
#pragma unroll
      for (int ni = 0; ni < 2; ++ni) {
        accG[mi][ni] = (f32x4){0.f,0.f,0.f,0.f};
        accU[mi][ni] = (f32x4){0.f,0.f,0.f,0.f};
      }

    for (int kc = 0; kc < H_DIM / BK; ++kc) {
      const int k0 = kc * BK;
      __syncthreads();
      // stage A: gathered token rows, 256x64 bf16 (16B per lane per iter, coalesced per row-seg)
      const int seg = tid & 7;
#pragma unroll
      for (int j = 0; j < 8; ++j) {
        int row = j*32 + (tid >> 3);
        uint4 v = *(const uint4*)(xb + (size_t)tok[j]*H_DIM + k0 + seg*8);
        *(uint4*)(sA + row*LDA + seg*8) = v;
      }
      // stage B: gate & up weight tiles, fp32 -> (w*scale) -> bf16
      const float sG = SgE[k0 >> 7];
      const float sU = SuE[k0 >> 7];
#pragma unroll
      for (int j = 0; j < 4; ++j) {
        int p = j*256 + tid;                // mat uniform per j (0,0,1,1)
        int mat = p >> 9;
        int row = (p >> 4) & 31;
        int sg4 = p & 15;
        const float* W = (mat ? WuE : WgE) + (size_t)row * H_DIM + k0 + sg4*4;
        float s = mat ? sU : sG;
        float4 v = *(const float4*)W;
        us4 o;
        o.x = f2bf(v.x * s); o.y = f2bf(v.y * s);
        o.z = f2bf(v.z * s); o.w = f2bf(v.w * s);
        *(us4*)(sB + (mat*TN + row)*LDA + sg4*4) = o;
      }
      __syncthreads();
#pragma unroll
      for (int ks = 0; ks < 2; ++ks) {
        bf16x8 a[4], bg[2], bu[2];
#pragma unroll
        for (int mi = 0; mi < 4; ++mi)
          a[mi] = *(const bf16x8*)(sA + (wv*64 + mi*16 + ln)*LDA + ks*32 + quad*8);
#pragma unroll
        for (int ni = 0; ni < 2; ++ni) {
          bg[ni] = *(const bf16x8*)(sB + (ni*16 + ln)*LDA + ks*32 + quad*8);
          bu[ni] = *(const bf16x8*)(sB + (TN + ni*16 + ln)*LDA + ks*32 + quad*8);
        }
#pragma unroll
        for (int mi = 0; mi < 4; ++mi)
#pragma unroll
          for (int ni = 0; ni < 2; ++ni) {
            accG[mi][ni] = __builtin_amdgcn_mfma_f32_16x16x32_bf16(a[mi], bg[ni], accG[mi][ni], 0, 0, 0);
            accU[mi][ni] = __builtin_amdgcn_mfma_f32_16x16x32_bf16(a[mi], bu[ni], accU[mi][ni], 0, 0, 0);
          }
      }
    }
    // epilogue: h = silu(g) * u * combine_weight  (C/D: col=lane&15, row=quad*4+reg)
#pragma unroll
    for (int mi = 0; mi < 4; ++mi)
#pragma unroll
      for (int r = 0; r < 4; ++r) {
        int m = m0 + wv*64 + mi*16 + quad*4 + r;
        if (m < cnt) {
          float c = cwE[m];
#pragma unroll
          for (int ni = 0; ni < 2; ++ni) {
            float g = accG[mi][ni][r];
            float u = accU[mi][ni][r];
            float h = g / (1.f + __expf(-g)) * u * c;
            HbE[(size_t)m * I_DIM + n0 + ni*16 + ln] = f2bf(h);
          }
        }
      }
  }
}

// ---------- down GEMM + scatter-add to output ----------
__global__ __launch_bounds__(256, 2)
void k_down(const unsigned short* __restrict__ Hbuf,
            const float* __restrict__ Wd, const float* __restrict__ Sd,
            const int* __restrict__ counts, const int* __restrict__ list,
            float* __restrict__ out) {
  __shared__ unsigned short sA[TM * LDA];
  __shared__ unsigned short sB[TN * LDA];
  const int e   = blockIdx.y;
  const int n0  = blockIdx.x * TN;
  const int cnt = counts[e];
  if (cnt == 0) return;
  const int tid  = threadIdx.x;
  const int wv   = tid >> 6;
  const int lane = tid & 63;
  const int quad = lane >> 4;
  const int ln   = lane & 15;

  const int* listE = list + e * CAP;
  const unsigned short* HbE = Hbuf + (size_t)e * CAP * I_DIM;
  const float* WdE = Wd + (size_t)e * H_DIM * I_DIM + (size_t)n0 * I_DIM;
  const float* SdE = Sd + e * (16*11) + (n0 >> 7) * 11;   // (E, H/128, I/128)

  for (int m0 = 0; m0 < cnt; m0 += TM) {
    f32x4 acc[4][2];
#pragma unroll
    for (int mi = 0; mi < 4; ++mi)
#pragma unroll
      for (int ni = 0; ni < 2; ++ni)
        acc[mi][ni] = (f32x4){0.f,0.f,0.f,0.f};

    for (int kc = 0; kc < I_DIM / BK; ++kc) {   // 22 chunks
      const int k0 = kc * BK;
      __syncthreads();
      const int seg = tid & 7;
#pragma unroll
      for (int j = 0; j < 8; ++j) {
        int row = j*32 + (tid >> 3);
        uint4 v = *(const uint4*)(HbE + (size_t)(m0 + row)*I_DIM + k0 + seg*8);
        *(uint4*)(sA + row*LDA + seg*8) = v;
      }
      const float s = SdE[k0 >> 7];
#pragma unroll
      for (int j = 0; j < 2; ++j) {
        int p = j*256 + tid;                // 0..511: 32 rows x 16 float4-segs
        int row = p >> 4;
        int sg4 = p & 15;
        float4 v = *(const float4*)(WdE + (size_t)row * I_DIM + k0 + sg4*4);
        us4 o;
        o.x = f2bf(v.x * s); o.y = f2bf(v.y * s);
        o.z = f2bf(v.z * s); o.w = f2bf(v.w * s);
        *(us4*)(sB + row*LDA + sg4*4) = o;
      }
      __syncthreads();
#pragma unroll
      for (int ks = 0; ks < 2; ++ks) {
        bf16x8 a[4], b[2];
#pragma unroll
        for (int mi = 0; mi < 4; ++mi)
          a[mi] = *(const bf16x8*)(sA + (wv*64 + mi*16 + ln)*LDA + ks*32 + quad*8);
#pragma unroll
        for (int ni = 0; ni < 2; ++ni)
          b[ni] = *(const bf16x8*)(sB + (ni*16 + ln)*LDA + ks*32 + quad*8);
#pragma unroll
        for (int mi = 0; mi < 4; ++mi)
#pragma unroll
          for (int ni = 0; ni < 2; ++ni)
            acc[mi][ni] = __builtin_amdgcn_mfma_f32_16x16x32_bf16(a[mi], b[ni], acc[mi][ni], 0, 0, 0);
      }
    }
    // epilogue: scatter-add (combine weight already folded into Hbuf)
#pragma unroll
    for (int mi = 0; mi < 4; ++mi)
#pragma unroll
      for (int r = 0; r < 4; ++r) {
        int m = m0 + wv*64 + mi*16 + quad*4 + r;
        if (m < cnt) {
          int t = listE[m];
#pragma unroll
          for (int ni = 0; ni < 2; ++ni)
            atomicAdd(out + (size_t)t * H_DIM + n0 + ni*16 + ln, acc[mi][ni][r]);
        }
      }
  }
}

extern "C" void kernel_launch(void* const* d_in, const int* in_sizes, int n_in,
                              void* d_out, int out_size, void* d_ws, size_t ws_size,
                              hipStream_t stream) {
  const float* x  = (const float*)d_in[0];
  const float* Wg = (const float*)d_in[1];
  const float* Sg = (const float*)d_in[2];
  const float* Wu = (const float*)d_in[3];
  const float* Su = (const float*)d_in[4];
  const float* Wd = (const float*)d_in[5];
  const float* Sd = (const float*)d_in[6];
  const float* rw = (const float*)d_in[7];
  const int*  sel = (const int*)d_in[8];
  float* out = (float*)d_out;

  char* ws = (char*)d_ws;
  int*   counts = (int*)ws;                                   // 64 B (zeroed below)
  int*   list   = (int*)(ws + 256);                           // 32 KB
  float* cw     = (float*)(ws + 256 + 32768);                 // 32 KB
  unsigned short* xb   = (unsigned short*)(ws + 256 + 65536); // 2 MB
  unsigned short* Hbuf = (unsigned short*)(ws + 256 + 65536 + (size_t)T_TOK*H_DIM*2); // ~22 MB
  (void)in_sizes; (void)n_in; (void)out_size; (void)ws_size;

  hipMemsetAsync(counts, 0, 256, stream);
  hipMemsetAsync(out, 0, sizeof(float) * (size_t)T_TOK * H_DIM, stream);
  k_routing<<<dim3((T_TOK + 255) / 256), dim3(256), 0, stream>>>(rw, sel, counts, list, cw);
  k_xcast<<<dim3((T_TOK * H_DIM) / 2048), dim3(256), 0, stream>>>(x, xb);
  k_gateup<<<dim3(I_DIM / TN, E_NUM), dim3(256), 0, stream>>>(xb, Wg, Sg, Wu, Su, counts, list, cw, Hbuf);
  k_down<<<dim3(H_DIM / TN, E_NUM), dim3(256), 0, stream>>>(Hbuf, Wd, Sd, counts, list, out);
}